// Round 15
// baseline (180.579 us; speedup 1.0000x reference)
//
#include <hip/hip_runtime.h>
#include <hip/hip_bf16.h>
#include <stdint.h>

// Problem constants
#define BATCH 2
#define NPTS 4096
#define DMODEL 1024
#define NHEAD 16
#define HDIM 64
#define KNN 16
#define MASKN 131072   // 32*64*64

typedef __attribute__((ext_vector_type(8))) short bf16x8;
typedef __attribute__((ext_vector_type(4))) float f32x4;

__device__ __forceinline__ float b2f(unsigned short u) {
    union { unsigned int i; float f; } c; c.i = ((unsigned int)u) << 16; return c.f;
}
__device__ __forceinline__ unsigned short f2b(float f) {
    unsigned int x = __float_as_uint(f);
    unsigned int r = (x + 0x7fffu + ((x >> 16) & 1u)) >> 16;
    return (unsigned short)r;
}
__device__ __forceinline__ unsigned int pack2f(float a, float b) {
    return (unsigned int)f2b(a) | ((unsigned int)f2b(b) << 16);
}
// async global->LDS, 16B per lane. lptr must be wave-uniform; HW writes lptr + lane*16.
__device__ __forceinline__ void gload16(const unsigned short* g, unsigned short* l) {
    __builtin_amdgcn_global_load_lds((const __attribute__((address_space(1))) void*)g,
                                     (__attribute__((address_space(3))) void*)l, 16, 0, 0);
}

// ---------------------------------------------------------------------------
// 1) Single-kernel active-index extraction: 128 blocks; each block re-derives
//    the global prefix from the full mask (16MB total, L2-broadcast) and
//    extracts its own 1024-elem segment. Handles byte-bool or int32 masks.
// ---------------------------------------------------------------------------
__global__ __launch_bounds__(256) void prep_kernel(const unsigned char* __restrict__ m8,
                                                   int* __restrict__ act) {
    __shared__ int sthr[256];
    const int b = blockIdx.x, t = threadIdx.x;
    // pass 1: byte counts; thread t covers elems [t*512, t*512+512)
    int cnt = 0;
    const uchar4* v8 = (const uchar4*)m8;
    for (int i = 0; i < 128; ++i) {
        const uchar4 v = v8[t * 128 + i];
        cnt += (v.x != 0) + (v.y != 0) + (v.z != 0) + (v.w != 0);
    }
    sthr[t] = cnt;
    __syncthreads();
    for (int off = 1; off < 256; off <<= 1) {
        int v = (t >= off) ? sthr[t - off] : 0;
        __syncthreads();
        sthr[t] += v;
        __syncthreads();
    }
    const bool bytes = (sthr[255] == NPTS);   // grid-uniform
    int blkoff;
    if (bytes) {
        blkoff = (b == 0) ? 0 : sthr[2 * b - 1];   // prefix of elems [0, b*1024)
        __syncthreads();
    } else {
        // int32-mask path: recount with int view
        __syncthreads();
        const int4* v32 = (const int4*)m8;
        int c2 = 0;
        for (int i = 0; i < 128; ++i) {
            const int4 v = v32[t * 128 + i];
            c2 += (v.x != 0) + (v.y != 0) + (v.z != 0) + (v.w != 0);
        }
        sthr[t] = c2;
        __syncthreads();
        for (int off = 1; off < 256; off <<= 1) {
            int v = (t >= off) ? sthr[t - off] : 0;
            __syncthreads();
            sthr[t] += v;
            __syncthreads();
        }
        blkoff = (b == 0) ? 0 : sthr[2 * b - 1];
        __syncthreads();
    }
    // extract own segment: elems [b*1024 + t*4, +4)
    const int gbase = b * 1024 + t * 4;
    int f0, f1, f2, f3;
    if (bytes) {
        const uchar4 v = ((const uchar4*)m8)[gbase >> 2];
        f0 = v.x != 0; f1 = v.y != 0; f2 = v.z != 0; f3 = v.w != 0;
    } else {
        const int4 v = ((const int4*)m8)[gbase >> 2];
        f0 = v.x != 0; f1 = v.y != 0; f2 = v.z != 0; f3 = v.w != 0;
    }
    const int c = f0 + f1 + f2 + f3;
    sthr[t] = c;
    __syncthreads();
    for (int off = 1; off < 256; off <<= 1) {
        int v = (t >= off) ? sthr[t - off] : 0;
        __syncthreads();
        sthr[t] += v;
        __syncthreads();
    }
    int pos = blkoff + sthr[t] - c;
    if (f0) act[pos++] = gbase;
    if (f1) act[pos++] = gbase + 1;
    if (f2) act[pos++] = gbase + 2;
    if (f3) act[pos++] = gbase + 3;
}

// ---------------------------------------------------------------------------
// 2) Fused kNN + cast: blocks 0..1023 run kNN (VALU-bound), blocks 1024+
//    run the f32->bf16 cast (HBM-bound) — co-resident, runtime ~= max.
// ---------------------------------------------------------------------------
#define XN8 (BATCH * NPTS * DMODEL / 8)   // 1048576 16B-chunks
#define WN8 (DMODEL * DMODEL / 8)         // 131072
#define CASTN (XN8 + 3 * WN8)             // 1441792
#define CASTBLKS ((CASTN + 255) / 256)    // 5632

__global__ __launch_bounds__(256) void knn_cast_kernel(
    const int* __restrict__ act, int* __restrict__ nbr,
    const float* __restrict__ x, const float* __restrict__ wq,
    const float* __restrict__ wk, const float* __restrict__ wv,
    unsigned short* __restrict__ Xb, unsigned short* __restrict__ Wb)
{
    __shared__ int act_s[NPTS];
    const int t = threadIdx.x;
    if (blockIdx.x < 1024) {
        // ---- kNN: 64 lanes/query, 4 queries/block ----
        for (int i = t; i < NPTS; i += 256) act_s[i] = act[i];
        __syncthreads();
        const int q = blockIdx.x * 4 + (t >> 6);
        const int lane = t & 63;
        const int aq = act_s[q];
        const int qz = aq >> 12, qy = (aq >> 6) & 63, qx = aq & 63;
        int best[17];
        #pragma unroll
        for (int i = 0; i < 17; ++i) best[i] = 0x7FFFFFFF;
        for (int j = lane; j < NPTS; j += 64) {
            const int aj = act_s[j];
            const int dz = (aj >> 12) - qz;
            const int dy = ((aj >> 6) & 63) - qy;
            const int dx = (aj & 63) - qx;
            const int d2 = dz * dz + dy * dy + dx * dx;
            int p = (d2 << 12) | j;
            if (p < best[16]) {
                #pragma unroll
                for (int u = 0; u < 17; ++u) {
                    const bool lt = p < best[u];
                    const int tmp = best[u];
                    best[u] = lt ? p : best[u];
                    p = lt ? tmp : p;
                }
            }
        }
        int head = best[0];
        int keep = 0;
        #pragma unroll
        for (int r = 0; r < KNN + 1; ++r) {
            int m = head;
            #pragma unroll
            for (int off = 32; off >= 1; off >>= 1) m = min(m, __shfl_xor(m, off, 64));
            if (lane == r - 1) keep = m;
            const bool win = (head == m);
            #pragma unroll
            for (int u = 0; u < 16; ++u) if (win) best[u] = best[u + 1];
            if (win) best[16] = 0x7FFFFFFF;
            head = best[0];
        }
        if (lane < KNN) nbr[q * KNN + lane] = keep & 4095;
    } else {
        // ---- cast: chunk i of {X, Wq, Wk, Wv} -> bf16 ----
        const int i = (blockIdx.x - 1024) * 256 + t;
        if (i >= CASTN) return;
        const float* src;
        unsigned short* dst;
        if (i < XN8) {
            src = x + (size_t)i * 8;
            dst = Xb + (size_t)i * 8;
        } else {
            const int j = i - XN8;
            const int wsel = j >> 17;          // /WN8
            const int o = j & (WN8 - 1);
            src = ((wsel == 0) ? wq : (wsel == 1) ? wk : wv) + (size_t)o * 8;
            dst = Wb + ((size_t)wsel * WN8 + o) * 8;
        }
        const float4 a = ((const float4*)src)[0];
        const float4 bb = ((const float4*)src)[1];
        uint4 w;
        w.x = pack2f(a.x, a.y);  w.y = pack2f(a.z, a.w);
        w.z = pack2f(bb.x, bb.y); w.w = pack2f(bb.z, bb.w);
        *(uint4*)dst = w;
    }
}

// ---------------------------------------------------------------------------
// 3) QKV GEMM (gemm_qkv64, R14 best): BK=64 dbuf, 8-way chunk-XOR swizzle
//    (conflict-free), counted vmcnt(8), 64KB LDS -> 2 blocks/CU.
// ---------------------------------------------------------------------------
__global__ __launch_bounds__(256, 2) void gemm_qkv64(
    const unsigned short* __restrict__ Xb,
    const unsigned short* __restrict__ Wb,   // 3 contiguous 1024x1024 bf16
    unsigned short* __restrict__ O0, unsigned short* __restrict__ O1, unsigned short* __restrict__ O2)
{
    const int K = DMODEL, N = DMODEL;
    const unsigned short* W = Wb + (size_t)blockIdx.z * DMODEL * DMODEL;
    unsigned short* C = (blockIdx.z == 0) ? O0 : (blockIdx.z == 1) ? O1 : O2;
    __shared__ unsigned short As[2][128 * 64];   // 32KB
    __shared__ unsigned short Bs[2][128 * 64];   // 32KB
    const int tid = threadIdx.x;
    const int rowBase = blockIdx.x * 128;
    const int colBase = blockIdx.y * 128;
    const int lane = tid & 63, w = tid >> 6;
    const int wr = w >> 1, wc = w & 1;
    const int lr = lane & 15, kg = lane >> 4;

    f32x4 acc[4][4];
    const f32x4 zero = {0.f, 0.f, 0.f, 0.f};
    #pragma unroll
    for (int i = 0; i < 4; ++i)
        #pragma unroll
        for (int j = 0; j < 4; ++j) acc[i][j] = zero;

    const unsigned short* aS[4];
    const unsigned short* bS[4];
    #pragma unroll
    for (int j = 0; j < 4; ++j) {
        const int s = j * 256 + tid;
        const int row = s >> 3, pch = s & 7;
        const int sc = (pch ^ (row & 7)) * 8;
        aS[j] = Xb + (size_t)(rowBase + row) * K + sc;
        bS[j] = W  + (size_t)(colBase + row) * K + sc;
    }

    #define STAGE(kt, bf) do { \
        _Pragma("unroll") \
        for (int j = 0; j < 4; ++j) { \
            gload16(aS[j] + (kt) * 64, &As[bf][(j * 256 + w * 64) * 8]); \
            gload16(bS[j] + (kt) * 64, &Bs[bf][(j * 256 + w * 64) * 8]); \
        } \
    } while (0)

    #define COMPUTE(bf) do { \
        bf16x8 af[4][2], bfr[4][2]; \
        _Pragma("unroll") \
        for (int mi = 0; mi < 4; ++mi) \
            _Pragma("unroll") \
            for (int kk = 0; kk < 2; ++kk) \
                af[mi][kk] = *(const bf16x8*)&As[bf][(wr * 64 + mi * 16 + lr) * 64 + (((kk * 4 + kg) ^ (lr & 7)) * 8)]; \
        _Pragma("unroll") \
        for (int ni = 0; ni < 4; ++ni) \
            _Pragma("unroll") \
            for (int kk = 0; kk < 2; ++kk) \
                bfr[ni][kk] = *(const bf16x8*)&Bs[bf][(wc * 64 + ni * 16 + lr) * 64 + (((kk * 4 + kg) ^ (lr & 7)) * 8)]; \
        __builtin_amdgcn_s_setprio(1); \
        _Pragma("unroll") \
        for (int kk = 0; kk < 2; ++kk) \
            _Pragma("unroll") \
            for (int mi = 0; mi < 4; ++mi) \
                _Pragma("unroll") \
                for (int ni = 0; ni < 4; ++ni) \
                    acc[mi][ni] = __builtin_amdgcn_mfma_f32_16x16x32_bf16(af[mi][kk], bfr[ni][kk], acc[mi][ni], 0, 0, 0); \
        __builtin_amdgcn_s_setprio(0); \
    } while (0)

    STAGE(0, 0);
    STAGE(1, 1);
    for (int kt = 0; kt < 14; ++kt) {
        const int bf = kt & 1;
        asm volatile("s_waitcnt vmcnt(8)" ::: "memory");
        __builtin_amdgcn_s_barrier();
        COMPUTE(bf);
        __builtin_amdgcn_s_barrier();
        STAGE(kt + 2, bf);
    }
    asm volatile("s_waitcnt vmcnt(8)" ::: "memory");
    __builtin_amdgcn_s_barrier();
    COMPUTE(0);
    __builtin_amdgcn_s_barrier();
    asm volatile("s_waitcnt vmcnt(0)" ::: "memory");
    __builtin_amdgcn_s_barrier();
    COMPUTE(1);
    #undef STAGE
    #undef COMPUTE

    #pragma unroll
    for (int mi = 0; mi < 4; ++mi)
        #pragma unroll
        for (int ni = 0; ni < 4; ++ni) {
            const int row0 = rowBase + wr * 64 + mi * 16 + kg * 4;
            const int col = colBase + wc * 64 + ni * 16 + lr;
            #pragma unroll
            for (int j = 0; j < 4; ++j)
                C[(size_t)(row0 + j) * N + col] = f2b(acc[mi][ni][j]);
        }
}

// ---------------------------------------------------------------------------
// 3c) FALLBACK f32-input GEMM (used only if ws too small for bf16 copies)
// ---------------------------------------------------------------------------
__device__ __forceinline__ void stage16(unsigned short* dst, const float* src) {
    const float4 a = ((const float4*)src)[0];
    const float4 b = ((const float4*)src)[1];
    const float4 c = ((const float4*)src)[2];
    const float4 d = ((const float4*)src)[3];
    uint4 w0, w1;
    w0.x = pack2f(a.x, a.y); w0.y = pack2f(a.z, a.w);
    w0.z = pack2f(b.x, b.y); w0.w = pack2f(b.z, b.w);
    w1.x = pack2f(c.x, c.y); w1.y = pack2f(c.z, c.w);
    w1.z = pack2f(d.x, d.y); w1.w = pack2f(d.z, d.w);
    ((uint4*)dst)[0] = w0;
    ((uint4*)dst)[1] = w1;
}

__global__ __launch_bounds__(256) void gemm_qkv_f32(
    const float* __restrict__ X,
    const float* __restrict__ W0, const float* __restrict__ W1, const float* __restrict__ W2,
    unsigned short* __restrict__ O0, unsigned short* __restrict__ O1, unsigned short* __restrict__ O2)
{
    const int K = DMODEL, N = DMODEL;
    const float* W = (blockIdx.z == 0) ? W0 : (blockIdx.z == 1) ? W1 : W2;
    unsigned short* C = (blockIdx.z == 0) ? O0 : (blockIdx.z == 1) ? O1 : O2;
    __shared__ unsigned short As[128 * 32];
    __shared__ unsigned short Bs[128 * 32];
    const int tid = threadIdx.x;
    const int rowBase = blockIdx.x * 128;
    const int colBase = blockIdx.y * 128;
    const int lane = tid & 63, w = tid >> 6;
    const int wr = w >> 1, wc = w & 1;
    const int lr = lane & 15, kg = lane >> 4;
    const int srow = tid >> 1;
    const int scol = (tid & 1) * 16;
    f32x4 acc[4][4];
    const f32x4 zero = {0.f, 0.f, 0.f, 0.f};
    #pragma unroll
    for (int i = 0; i < 4; ++i)
        #pragma unroll
        for (int j = 0; j < 4; ++j) acc[i][j] = zero;
    const float* Arow = &X[(size_t)(rowBase + srow) * K + scol];
    const float* Brow = &W[(size_t)(colBase + srow) * K + scol];
    unsigned short* Adst = &As[srow * 32 + scol];
    unsigned short* Bdst = &Bs[srow * 32 + scol];
    for (int kb = 0; kb < K; kb += 32) {
        __syncthreads();
        stage16(Adst, Arow + kb);
        stage16(Bdst, Brow + kb);
        __syncthreads();
        bf16x8 af[4], bfr[4];
        #pragma unroll
        for (int mi = 0; mi < 4; ++mi)
            af[mi] = *(const bf16x8*)&As[(wr * 64 + mi * 16 + lr) * 32 + kg * 8];
        #pragma unroll
        for (int ni = 0; ni < 4; ++ni)
            bfr[ni] = *(const bf16x8*)&Bs[(wc * 64 + ni * 16 + lr) * 32 + kg * 8];
        #pragma unroll
        for (int mi = 0; mi < 4; ++mi)
            #pragma unroll
            for (int ni = 0; ni < 4; ++ni)
                acc[mi][ni] = __builtin_amdgcn_mfma_f32_16x16x32_bf16(af[mi], bfr[ni], acc[mi][ni], 0, 0, 0);
    }
    #pragma unroll
    for (int mi = 0; mi < 4; ++mi)
        #pragma unroll
        for (int ni = 0; ni < 4; ++ni) {
            const int row0 = rowBase + wr * 64 + mi * 16 + kg * 4;
            const int col = colBase + wc * 64 + ni * 16 + lr;
            #pragma unroll
            for (int j = 0; j < 4; ++j)
                C[(size_t)(row0 + j) * N + col] = f2b(acc[mi][ni][j]);
        }
}

// ---------------------------------------------------------------------------
// 4) Attention v5: K fragments in REGISTERS (early-issued, like V) — no K
//    LDS round-trip. Neighbor ids via one nbr load + 16-wide shfl.
//    XCD-chunked block mapping; fused metric epilogue.
// ---------------------------------------------------------------------------
__global__ __launch_bounds__(256) void attn_kernel(
    const unsigned short* __restrict__ Q, const unsigned short* __restrict__ Kb,
    const unsigned short* __restrict__ Vb, const int* __restrict__ nbr,
    float* __restrict__ out, float* __restrict__ mout)
{
    const int bid = blockIdx.x;
    const int p = (bid & 7) * 1024 + (bid >> 3);   // bijective: 8192 = 8 XCDs x 1024
    const int b = p >> 12;
    const int n = p & 4095;
    __shared__ unsigned short q_s[DMODEL];        // 2KB
    __shared__ float a_s[NHEAD][KNN];             // 1KB
    __shared__ float part_s[4][64];               // 1KB (metric partials)
    const int tid = threadIdx.x;
    const int kk = tid & 15, h = tid >> 4;
    const int mynb = nbr[n * KNN + kk];
    // --- early-issue K fragments into registers: row nb[kk], head-slice h ---
    const unsigned short* krow = &Kb[((size_t)b * NPTS + mynb) * DMODEL + h * HDIM];
    bf16x8 kreg[8];
    #pragma unroll
    for (int j = 0; j < 8; ++j) kreg[j] = *(const bf16x8*)&krow[j * 8];
    // --- early-issue V fragments: thread owns output dims o = tid*4..+3 ---
    const int o = tid * 4;
    ushort4 vpre[KNN];
    #pragma unroll
    for (int k2 = 0; k2 < KNN; ++k2) {
        const int nb2 = __shfl(mynb, k2, 16);
        vpre[k2] = *(const ushort4*)&Vb[((size_t)b * NPTS + nb2) * DMODEL + o];
    }
    // --- stage q (16x reuse -> LDS) ---
    *(int2*)&q_s[tid * 4] = *(const int2*)&Q[((size_t)b * NPTS + n) * DMODEL + tid * 4];
    __syncthreads();
    // --- scores: thread (h,kk); q broadcast from LDS, K from registers ---
    float s = 0.f;
    #pragma unroll
    for (int j = 0; j < 8; ++j) {
        const bf16x8 qq = *(const bf16x8*)&q_s[h * HDIM + j * 8];
        const bf16x8 kr = kreg[j];
        #pragma unroll
        for (int e = 0; e < 8; ++e)
            s += b2f((unsigned short)qq[e]) * b2f((unsigned short)kr[e]);
    }
    s *= 0.125f;  // 1/sqrt(64)
    float m = s;
    #pragma unroll
    for (int off = 8; off >= 1; off >>= 1) m = fmaxf(m, __shfl_xor(m, off, 16));
    const float e = __expf(s - m);
    float sum = e;
    #pragma unroll
    for (int off = 8; off >= 1; off >>= 1) sum += __shfl_xor(sum, off, 16);
    a_s[h][kk] = e / sum;
    __syncthreads();
    // --- PV: pure VALU from preloaded regs + a_s broadcasts ---
    const int h2 = tid >> 4;        // == o>>6
    float av0 = 0.f, av1 = 0.f, av2 = 0.f, av3 = 0.f;
    #pragma unroll
    for (int k2 = 0; k2 < KNN; ++k2) {
        const float a = a_s[h2][k2];
        av0 += a * b2f(vpre[k2].x); av1 += a * b2f(vpre[k2].y);
        av2 += a * b2f(vpre[k2].z); av3 += a * b2f(vpre[k2].w);
    }
    float4 r; r.x = av0; r.y = av1; r.z = av2; r.w = av3;
    *(float4*)&out[((size_t)b * NPTS + n) * DMODEL + o] = r;
    // --- fused metric: mout[b,n,d] = (1/16) sum_h Kb[b,n,h*64+d] ---
    {
        const unsigned short* krow2 = &Kb[((size_t)b * NPTS + n) * DMODEL];
        const int dd = tid & 63, grp = tid >> 6;
        float ms = 0.f;
        #pragma unroll
        for (int hh = 0; hh < 4; ++hh)
            ms += b2f(krow2[(grp * 4 + hh) * HDIM + dd]);
        part_s[grp][dd] = ms;
        __syncthreads();
        if (tid < 64)
            mout[((size_t)b * NPTS + n) * HDIM + tid] =
                (part_s[0][tid] + part_s[1][tid] + part_s[2][tid] + part_s[3][tid]) * 0.0625f;
    }
}

// ---------------------------------------------------------------------------
extern "C" void kernel_launch(void* const* d_in, const int* in_sizes, int n_in,
                              void* d_out, int out_size, void* d_ws, size_t ws_size,
                              hipStream_t stream) {
    const float* x = (const float*)d_in[0];
    const unsigned char* mask = (const unsigned char*)d_in[1];
    const float* Wq = (const float*)d_in[2];
    const float* Wk = (const float*)d_in[3];
    const float* Wv = (const float*)d_in[4];
    float* out = (float*)d_out;
    char* ws = (char*)d_ws;

    const size_t QKV_BYTES = (size_t)BATCH * NPTS * DMODEL * 2;   // 16.78 MB each
    const size_t XB_BYTES  = (size_t)BATCH * NPTS * DMODEL * 2;   // 16.78 MB
    const size_t WB_BYTES  = (size_t)3 * DMODEL * DMODEL * 2;     // 6.29 MB
    unsigned short* qb = (unsigned short*)(ws);
    unsigned short* kb = (unsigned short*)(ws + QKV_BYTES);
    unsigned short* vb = (unsigned short*)(ws + 2 * QKV_BYTES);
    const size_t SMALL_BYTES = (size_t)NPTS * sizeof(int) * (1 + KNN);
    const size_t need_base = 3 * QKV_BYTES + SMALL_BYTES;
    const size_t need_full = need_base + XB_BYTES + WB_BYTES;
    const bool full = (ws_size >= need_full);
    char* tail = ws + 3 * QKV_BYTES;
    unsigned short* Xb = (unsigned short*)tail;
    unsigned short* Wb = (unsigned short*)(tail + XB_BYTES);
    char* small = full ? (tail + XB_BYTES + WB_BYTES) : tail;
    int* act  = (int*)small;
    int* nbr  = (int*)(small + NPTS * sizeof(int));
    if (ws_size < need_base) return;

    prep_kernel<<<128, 256, 0, stream>>>(mask, act);
    if (full) {
        knn_cast_kernel<<<1024 + CASTBLKS, 256, 0, stream>>>(act, nbr, x, Wq, Wk, Wv, Xb, Wb);
        gemm_qkv64<<<dim3(64, 8, 3), 256, 0, stream>>>(Xb, Wb, qb, kb, vb);
    } else {
        knn_cast_kernel<<<1024, 256, 0, stream>>>(act, nbr, x, Wq, Wk, Wv,
                                                  (unsigned short*)nullptr, (unsigned short*)nullptr);
        gemm_qkv_f32<<<dim3(64, 8, 3), 256, 0, stream>>>(x, Wq, Wk, Wv, qb, kb, vb);
    }
    attn_kernel<<<dim3(BATCH * NPTS), 256, 0, stream>>>(qb, kb, vb, nbr, out,
                                                        out + (size_t)BATCH * NPTS * DMODEL);
}

// Round 16
// 167.262 us; speedup vs baseline: 1.0796x; 1.0796x over previous
//
#include <hip/hip_runtime.h>
#include <hip/hip_bf16.h>
#include <stdint.h>

// Problem constants
#define BATCH 2
#define NPTS 4096
#define DMODEL 1024
#define NHEAD 16
#define HDIM 64
#define KNN 16
#define MASKN 131072   // 32*64*64
#define EBLK 128       // extraction blocks (1024 mask elems each)

typedef __attribute__((ext_vector_type(8))) short bf16x8;
typedef __attribute__((ext_vector_type(4))) float f32x4;

__device__ __forceinline__ float b2f(unsigned short u) {
    union { unsigned int i; float f; } c; c.i = ((unsigned int)u) << 16; return c.f;
}
__device__ __forceinline__ unsigned short f2b(float f) {
    unsigned int x = __float_as_uint(f);
    unsigned int r = (x + 0x7fffu + ((x >> 16) & 1u)) >> 16;
    return (unsigned short)r;
}
__device__ __forceinline__ unsigned int pack2f(float a, float b) {
    return (unsigned int)f2b(a) | ((unsigned int)f2b(b) << 16);
}
// async global->LDS, 16B per lane. lptr must be wave-uniform; HW writes lptr + lane*16.
__device__ __forceinline__ void gload16(const unsigned short* g, unsigned short* l) {
    __builtin_amdgcn_global_load_lds((const __attribute__((address_space(1))) void*)g,
                                     (__attribute__((address_space(3))) void*)l, 16, 0, 0);
}

// ---------------------------------------------------------------------------
// 1) Parallel active-index extraction (3 tiny kernels, R14-proven)
// ---------------------------------------------------------------------------
__global__ __launch_bounds__(256) void count8_kernel(const unsigned char* __restrict__ m8,
                                                     int* __restrict__ cnt8) {
    __shared__ int red[256];
    const int b = blockIdx.x, t = threadIdx.x;
    const uchar4 v = ((const uchar4*)m8)[b * 256 + t];
    red[t] = (v.x != 0) + (v.y != 0) + (v.z != 0) + (v.w != 0);
    __syncthreads();
    for (int off = 128; off >= 1; off >>= 1) {
        if (t < off) red[t] += red[t + off];
        __syncthreads();
    }
    if (t == 0) cnt8[b] = red[0];
}

__global__ __launch_bounds__(256) void count32_kernel(const unsigned char* __restrict__ m8,
                                                      const int* __restrict__ cnt8,
                                                      int* __restrict__ cnt32) {
    __shared__ int red[256];
    const int b = blockIdx.x, t = threadIdx.x;
    red[t] = (t < EBLK) ? cnt8[t] : 0;
    __syncthreads();
    for (int off = 128; off >= 1; off >>= 1) {
        if (t < off) red[t] += red[t + off];
        __syncthreads();
    }
    if (red[0] == NPTS) return;     // mask is byte-bool; int view would be OOB
    __syncthreads();
    const int4 v = ((const int4*)m8)[b * 256 + t];
    red[t] = (v.x != 0) + (v.y != 0) + (v.z != 0) + (v.w != 0);
    __syncthreads();
    for (int off = 128; off >= 1; off >>= 1) {
        if (t < off) red[t] += red[t + off];
        __syncthreads();
    }
    if (t == 0) cnt32[b] = red[0];
}

__global__ __launch_bounds__(256) void extract_kernel(const unsigned char* __restrict__ m8,
                                                      const int* __restrict__ cnt8,
                                                      const int* __restrict__ cnt32,
                                                      int* __restrict__ act) {
    __shared__ int sblk[EBLK];
    __shared__ int sthr[256];
    const int b = blockIdx.x, t = threadIdx.x;
    if (t < EBLK) sblk[t] = cnt8[t];
    __syncthreads();
    for (int off = 1; off < EBLK; off <<= 1) {
        int v = (t < EBLK && t >= off) ? sblk[t - off] : 0;
        __syncthreads();
        if (t < EBLK) sblk[t] += v;
        __syncthreads();
    }
    const bool bytes = (sblk[EBLK - 1] == NPTS);   // grid-uniform
    if (!bytes) {
        __syncthreads();
        if (t < EBLK) sblk[t] = cnt32[t];
        __syncthreads();
        for (int off = 1; off < EBLK; off <<= 1) {
            int v = (t < EBLK && t >= off) ? sblk[t - off] : 0;
            __syncthreads();
            if (t < EBLK) sblk[t] += v;
            __syncthreads();
        }
    }
    const int blkoff = (b == 0) ? 0 : sblk[b - 1];
    const int gbase = b * 1024 + t * 4;
    int f0, f1, f2, f3;
    if (bytes) {
        const uchar4 v = ((const uchar4*)m8)[b * 256 + t];
        f0 = v.x != 0; f1 = v.y != 0; f2 = v.z != 0; f3 = v.w != 0;
    } else {
        const int4 v = ((const int4*)m8)[b * 256 + t];
        f0 = v.x != 0; f1 = v.y != 0; f2 = v.z != 0; f3 = v.w != 0;
    }
    const int c = f0 + f1 + f2 + f3;
    sthr[t] = c;
    __syncthreads();
    for (int off = 1; off < 256; off <<= 1) {
        int v = (t >= off) ? sthr[t - off] : 0;
        __syncthreads();
        sthr[t] += v;
        __syncthreads();
    }
    int pos = blkoff + sthr[t] - c;
    if (f0) act[pos++] = gbase;
    if (f1) act[pos++] = gbase + 1;
    if (f2) act[pos++] = gbase + 2;
    if (f3) act[pos++] = gbase + 3;
}

// ---------------------------------------------------------------------------
// 2) Fused kNN + cast: blocks 0..1023 run kNN (VALU-bound), blocks 1024+
//    run the f32->bf16 cast (HBM-bound) — co-resident, runtime ~= max.
// ---------------------------------------------------------------------------
#define XN8 (BATCH * NPTS * DMODEL / 8)   // 1048576 16B-chunks
#define WN8 (DMODEL * DMODEL / 8)         // 131072
#define CASTN (XN8 + 3 * WN8)             // 1441792
#define CASTBLKS ((CASTN + 255) / 256)    // 5632

__global__ __launch_bounds__(256) void knn_cast_kernel(
    const int* __restrict__ act, int* __restrict__ nbr,
    const float* __restrict__ x, const float* __restrict__ wq,
    const float* __restrict__ wk, const float* __restrict__ wv,
    unsigned short* __restrict__ Xb, unsigned short* __restrict__ Wb)
{
    __shared__ int act_s[NPTS];
    const int t = threadIdx.x;
    if (blockIdx.x < 1024) {
        // ---- kNN: 64 lanes/query, 4 queries/block ----
        for (int i = t; i < NPTS; i += 256) act_s[i] = act[i];
        __syncthreads();
        const int q = blockIdx.x * 4 + (t >> 6);
        const int lane = t & 63;
        const int aq = act_s[q];
        const int qz = aq >> 12, qy = (aq >> 6) & 63, qx = aq & 63;
        int best[17];
        #pragma unroll
        for (int i = 0; i < 17; ++i) best[i] = 0x7FFFFFFF;
        for (int j = lane; j < NPTS; j += 64) {
            const int aj = act_s[j];
            const int dz = (aj >> 12) - qz;
            const int dy = ((aj >> 6) & 63) - qy;
            const int dx = (aj & 63) - qx;
            const int d2 = dz * dz + dy * dy + dx * dx;
            int p = (d2 << 12) | j;
            if (p < best[16]) {
                #pragma unroll
                for (int u = 0; u < 17; ++u) {
                    const bool lt = p < best[u];
                    const int tmp = best[u];
                    best[u] = lt ? p : best[u];
                    p = lt ? tmp : p;
                }
            }
        }
        int head = best[0];
        int keep = 0;
        #pragma unroll
        for (int r = 0; r < KNN + 1; ++r) {
            int m = head;
            #pragma unroll
            for (int off = 32; off >= 1; off >>= 1) m = min(m, __shfl_xor(m, off, 64));
            if (lane == r - 1) keep = m;
            const bool win = (head == m);
            #pragma unroll
            for (int u = 0; u < 16; ++u) if (win) best[u] = best[u + 1];
            if (win) best[16] = 0x7FFFFFFF;
            head = best[0];
        }
        if (lane < KNN) nbr[q * KNN + lane] = keep & 4095;
    } else {
        // ---- cast: chunk i of {X, Wq, Wk, Wv} -> bf16 ----
        const int i = (blockIdx.x - 1024) * 256 + t;
        if (i >= CASTN) return;
        const float* src;
        unsigned short* dst;
        if (i < XN8) {
            src = x + (size_t)i * 8;
            dst = Xb + (size_t)i * 8;
        } else {
            const int j = i - XN8;
            const int wsel = j >> 17;          // /WN8
            const int o = j & (WN8 - 1);
            src = ((wsel == 0) ? wq : (wsel == 1) ? wk : wv) + (size_t)o * 8;
            dst = Wb + ((size_t)wsel * WN8 + o) * 8;
        }
        const float4 a = ((const float4*)src)[0];
        const float4 bb = ((const float4*)src)[1];
        uint4 w;
        w.x = pack2f(a.x, a.y);  w.y = pack2f(a.z, a.w);
        w.z = pack2f(bb.x, bb.y); w.w = pack2f(bb.z, bb.w);
        *(uint4*)dst = w;
    }
}

// ---------------------------------------------------------------------------
// 3) QKV GEMM (gemm_qkv64, R14 best): BK=64 dbuf, 8-way chunk-XOR swizzle
//    (conflict-free), counted vmcnt(8), 64KB LDS -> 2 blocks/CU.
// ---------------------------------------------------------------------------
__global__ __launch_bounds__(256, 2) void gemm_qkv64(
    const unsigned short* __restrict__ Xb,
    const unsigned short* __restrict__ Wb,   // 3 contiguous 1024x1024 bf16
    unsigned short* __restrict__ O0, unsigned short* __restrict__ O1, unsigned short* __restrict__ O2)
{
    const int K = DMODEL, N = DMODEL;
    const unsigned short* W = Wb + (size_t)blockIdx.z * DMODEL * DMODEL;
    unsigned short* C = (blockIdx.z == 0) ? O0 : (blockIdx.z == 1) ? O1 : O2;
    __shared__ unsigned short As[2][128 * 64];   // 32KB
    __shared__ unsigned short Bs[2][128 * 64];   // 32KB
    const int tid = threadIdx.x;
    const int rowBase = blockIdx.x * 128;
    const int colBase = blockIdx.y * 128;
    const int lane = tid & 63, w = tid >> 6;
    const int wr = w >> 1, wc = w & 1;
    const int lr = lane & 15, kg = lane >> 4;

    f32x4 acc[4][4];
    const f32x4 zero = {0.f, 0.f, 0.f, 0.f};
    #pragma unroll
    for (int i = 0; i < 4; ++i)
        #pragma unroll
        for (int j = 0; j < 4; ++j) acc[i][j] = zero;

    const unsigned short* aS[4];
    const unsigned short* bS[4];
    #pragma unroll
    for (int j = 0; j < 4; ++j) {
        const int s = j * 256 + tid;
        const int row = s >> 3, pch = s & 7;
        const int sc = (pch ^ (row & 7)) * 8;
        aS[j] = Xb + (size_t)(rowBase + row) * K + sc;
        bS[j] = W  + (size_t)(colBase + row) * K + sc;
    }

    #define STAGE(kt, bf) do { \
        _Pragma("unroll") \
        for (int j = 0; j < 4; ++j) { \
            gload16(aS[j] + (kt) * 64, &As[bf][(j * 256 + w * 64) * 8]); \
            gload16(bS[j] + (kt) * 64, &Bs[bf][(j * 256 + w * 64) * 8]); \
        } \
    } while (0)

    #define COMPUTE(bf) do { \
        bf16x8 af[4][2], bfr[4][2]; \
        _Pragma("unroll") \
        for (int mi = 0; mi < 4; ++mi) \
            _Pragma("unroll") \
            for (int kk = 0; kk < 2; ++kk) \
                af[mi][kk] = *(const bf16x8*)&As[bf][(wr * 64 + mi * 16 + lr) * 64 + (((kk * 4 + kg) ^ (lr & 7)) * 8)]; \
        _Pragma("unroll") \
        for (int ni = 0; ni < 4; ++ni) \
            _Pragma("unroll") \
            for (int kk = 0; kk < 2; ++kk) \
                bfr[ni][kk] = *(const bf16x8*)&Bs[bf][(wc * 64 + ni * 16 + lr) * 64 + (((kk * 4 + kg) ^ (lr & 7)) * 8)]; \
        __builtin_amdgcn_s_setprio(1); \
        _Pragma("unroll") \
        for (int kk = 0; kk < 2; ++kk) \
            _Pragma("unroll") \
            for (int mi = 0; mi < 4; ++mi) \
                _Pragma("unroll") \
                for (int ni = 0; ni < 4; ++ni) \
                    acc[mi][ni] = __builtin_amdgcn_mfma_f32_16x16x32_bf16(af[mi][kk], bfr[ni][kk], acc[mi][ni], 0, 0, 0); \
        __builtin_amdgcn_s_setprio(0); \
    } while (0)

    STAGE(0, 0);
    STAGE(1, 1);
    for (int kt = 0; kt < 14; ++kt) {
        const int bf = kt & 1;
        asm volatile("s_waitcnt vmcnt(8)" ::: "memory");
        __builtin_amdgcn_s_barrier();
        COMPUTE(bf);
        __builtin_amdgcn_s_barrier();
        STAGE(kt + 2, bf);
    }
    asm volatile("s_waitcnt vmcnt(8)" ::: "memory");
    __builtin_amdgcn_s_barrier();
    COMPUTE(0);
    __builtin_amdgcn_s_barrier();
    asm volatile("s_waitcnt vmcnt(0)" ::: "memory");
    __builtin_amdgcn_s_barrier();
    COMPUTE(1);
    #undef STAGE
    #undef COMPUTE

    #pragma unroll
    for (int mi = 0; mi < 4; ++mi)
        #pragma unroll
        for (int ni = 0; ni < 4; ++ni) {
            const int row0 = rowBase + wr * 64 + mi * 16 + kg * 4;
            const int col = colBase + wc * 64 + ni * 16 + lr;
            #pragma unroll
            for (int j = 0; j < 4; ++j)
                C[(size_t)(row0 + j) * N + col] = f2b(acc[mi][ni][j]);
        }
}

// ---------------------------------------------------------------------------
// 3c) FALLBACK f32-input GEMM (used only if ws too small for bf16 copies)
// ---------------------------------------------------------------------------
__device__ __forceinline__ void stage16(unsigned short* dst, const float* src) {
    const float4 a = ((const float4*)src)[0];
    const float4 b = ((const float4*)src)[1];
    const float4 c = ((const float4*)src)[2];
    const float4 d = ((const float4*)src)[3];
    uint4 w0, w1;
    w0.x = pack2f(a.x, a.y); w0.y = pack2f(a.z, a.w);
    w0.z = pack2f(b.x, b.y); w0.w = pack2f(b.z, b.w);
    w1.x = pack2f(c.x, c.y); w1.y = pack2f(c.z, c.w);
    w1.z = pack2f(d.x, d.y); w1.w = pack2f(d.z, d.w);
    ((uint4*)dst)[0] = w0;
    ((uint4*)dst)[1] = w1;
}

__global__ __launch_bounds__(256) void gemm_qkv_f32(
    const float* __restrict__ X,
    const float* __restrict__ W0, const float* __restrict__ W1, const float* __restrict__ W2,
    unsigned short* __restrict__ O0, unsigned short* __restrict__ O1, unsigned short* __restrict__ O2)
{
    const int K = DMODEL, N = DMODEL;
    const float* W = (blockIdx.z == 0) ? W0 : (blockIdx.z == 1) ? W1 : W2;
    unsigned short* C = (blockIdx.z == 0) ? O0 : (blockIdx.z == 1) ? O1 : O2;
    __shared__ unsigned short As[128 * 32];
    __shared__ unsigned short Bs[128 * 32];
    const int tid = threadIdx.x;
    const int rowBase = blockIdx.x * 128;
    const int colBase = blockIdx.y * 128;
    const int lane = tid & 63, w = tid >> 6;
    const int wr = w >> 1, wc = w & 1;
    const int lr = lane & 15, kg = lane >> 4;
    const int srow = tid >> 1;
    const int scol = (tid & 1) * 16;
    f32x4 acc[4][4];
    const f32x4 zero = {0.f, 0.f, 0.f, 0.f};
    #pragma unroll
    for (int i = 0; i < 4; ++i)
        #pragma unroll
        for (int j = 0; j < 4; ++j) acc[i][j] = zero;
    const float* Arow = &X[(size_t)(rowBase + srow) * K + scol];
    const float* Brow = &W[(size_t)(colBase + srow) * K + scol];
    unsigned short* Adst = &As[srow * 32 + scol];
    unsigned short* Bdst = &Bs[srow * 32 + scol];
    for (int kb = 0; kb < K; kb += 32) {
        __syncthreads();
        stage16(Adst, Arow + kb);
        stage16(Bdst, Brow + kb);
        __syncthreads();
        bf16x8 af[4], bfr[4];
        #pragma unroll
        for (int mi = 0; mi < 4; ++mi)
            af[mi] = *(const bf16x8*)&As[(wr * 64 + mi * 16 + lr) * 32 + kg * 8];
        #pragma unroll
        for (int ni = 0; ni < 4; ++ni)
            bfr[ni] = *(const bf16x8*)&Bs[(wc * 64 + ni * 16 + lr) * 32 + kg * 8];
        #pragma unroll
        for (int mi = 0; mi < 4; ++mi)
            #pragma unroll
            for (int ni = 0; ni < 4; ++ni)
                acc[mi][ni] = __builtin_amdgcn_mfma_f32_16x16x32_bf16(af[mi], bfr[ni], acc[mi][ni], 0, 0, 0);
    }
    #pragma unroll
    for (int mi = 0; mi < 4; ++mi)
        #pragma unroll
        for (int ni = 0; ni < 4; ++ni) {
            const int row0 = rowBase + wr * 64 + mi * 16 + kg * 4;
            const int col = colBase + wc * 64 + ni * 16 + lr;
            #pragma unroll
            for (int j = 0; j < 4; ++j)
                C[(size_t)(row0 + j) * N + col] = f2b(acc[mi][ni][j]);
        }
}

// ---------------------------------------------------------------------------
// 4) Attention v5: K fragments in REGISTERS (early-issued, like V) — no K
//    LDS round-trip. Neighbor ids via one nbr load + 16-wide shfl.
//    XCD-chunked block mapping; fused metric epilogue.
// ---------------------------------------------------------------------------
__global__ __launch_bounds__(256) void attn_kernel(
    const unsigned short* __restrict__ Q, const unsigned short* __restrict__ Kb,
    const unsigned short* __restrict__ Vb, const int* __restrict__ nbr,
    float* __restrict__ out, float* __restrict__ mout)
{
    const int bid = blockIdx.x;
    const int p = (bid & 7) * 1024 + (bid >> 3);   // bijective: 8192 = 8 XCDs x 1024
    const int b = p >> 12;
    const int n = p & 4095;
    __shared__ unsigned short q_s[DMODEL];        // 2KB
    __shared__ float a_s[NHEAD][KNN];             // 1KB
    __shared__ float part_s[4][64];               // 1KB (metric partials)
    const int tid = threadIdx.x;
    const int kk = tid & 15, h = tid >> 4;
    const int mynb = nbr[n * KNN + kk];
    // --- early-issue K fragments into registers: row nb[kk], head-slice h ---
    const unsigned short* krow = &Kb[((size_t)b * NPTS + mynb) * DMODEL + h * HDIM];
    bf16x8 kreg[8];
    #pragma unroll
    for (int j = 0; j < 8; ++j) kreg[j] = *(const bf16x8*)&krow[j * 8];
    // --- early-issue V fragments: thread owns output dims o = tid*4..+3 ---
    const int o = tid * 4;
    ushort4 vpre[KNN];
    #pragma unroll
    for (int k2 = 0; k2 < KNN; ++k2) {
        const int nb2 = __shfl(mynb, k2, 16);
        vpre[k2] = *(const ushort4*)&Vb[((size_t)b * NPTS + nb2) * DMODEL + o];
    }
    // --- stage q (16x reuse -> LDS) ---
    *(int2*)&q_s[tid * 4] = *(const int2*)&Q[((size_t)b * NPTS + n) * DMODEL + tid * 4];
    __syncthreads();
    // --- scores: thread (h,kk); q broadcast from LDS, K from registers ---
    float s = 0.f;
    #pragma unroll
    for (int j = 0; j < 8; ++j) {
        const bf16x8 qq = *(const bf16x8*)&q_s[h * HDIM + j * 8];
        const bf16x8 kr = kreg[j];
        #pragma unroll
        for (int e = 0; e < 8; ++e)
            s += b2f((unsigned short)qq[e]) * b2f((unsigned short)kr[e]);
    }
    s *= 0.125f;  // 1/sqrt(64)
    float m = s;
    #pragma unroll
    for (int off = 8; off >= 1; off >>= 1) m = fmaxf(m, __shfl_xor(m, off, 16));
    const float e = __expf(s - m);
    float sum = e;
    #pragma unroll
    for (int off = 8; off >= 1; off >>= 1) sum += __shfl_xor(sum, off, 16);
    a_s[h][kk] = e / sum;
    __syncthreads();
    // --- PV: pure VALU from preloaded regs + a_s broadcasts ---
    const int h2 = tid >> 4;        // == o>>6
    float av0 = 0.f, av1 = 0.f, av2 = 0.f, av3 = 0.f;
    #pragma unroll
    for (int k2 = 0; k2 < KNN; ++k2) {
        const float a = a_s[h2][k2];
        av0 += a * b2f(vpre[k2].x); av1 += a * b2f(vpre[k2].y);
        av2 += a * b2f(vpre[k2].z); av3 += a * b2f(vpre[k2].w);
    }
    float4 r; r.x = av0; r.y = av1; r.z = av2; r.w = av3;
    *(float4*)&out[((size_t)b * NPTS + n) * DMODEL + o] = r;
    // --- fused metric: mout[b,n,d] = (1/16) sum_h Kb[b,n,h*64+d] ---
    {
        const unsigned short* krow2 = &Kb[((size_t)b * NPTS + n) * DMODEL];
        const int dd = tid & 63, grp = tid >> 6;
        float ms = 0.f;
        #pragma unroll
        for (int hh = 0; hh < 4; ++hh)
            ms += b2f(krow2[(grp * 4 + hh) * HDIM + dd]);
        part_s[grp][dd] = ms;
        __syncthreads();
        if (tid < 64)
            mout[((size_t)b * NPTS + n) * HDIM + tid] =
                (part_s[0][tid] + part_s[1][tid] + part_s[2][tid] + part_s[3][tid]) * 0.0625f;
    }
}

// ---------------------------------------------------------------------------
extern "C" void kernel_launch(void* const* d_in, const int* in_sizes, int n_in,
                              void* d_out, int out_size, void* d_ws, size_t ws_size,
                              hipStream_t stream) {
    const float* x = (const float*)d_in[0];
    const unsigned char* mask = (const unsigned char*)d_in[1];
    const float* Wq = (const float*)d_in[2];
    const float* Wk = (const float*)d_in[3];
    const float* Wv = (const float*)d_in[4];
    float* out = (float*)d_out;
    char* ws = (char*)d_ws;

    const size_t QKV_BYTES = (size_t)BATCH * NPTS * DMODEL * 2;   // 16.78 MB each
    const size_t XB_BYTES  = (size_t)BATCH * NPTS * DMODEL * 2;   // 16.78 MB
    const size_t WB_BYTES  = (size_t)3 * DMODEL * DMODEL * 2;     // 6.29 MB
    unsigned short* qb = (unsigned short*)(ws);
    unsigned short* kb = (unsigned short*)(ws + QKV_BYTES);
    unsigned short* vb = (unsigned short*)(ws + 2 * QKV_BYTES);
    const size_t SMALL_BYTES = (size_t)NPTS * sizeof(int) * (1 + KNN) + 2 * EBLK * sizeof(int);
    const size_t need_base = 3 * QKV_BYTES + SMALL_BYTES;
    const size_t need_full = need_base + XB_BYTES + WB_BYTES;
    const bool full = (ws_size >= need_full);
    char* tail = ws + 3 * QKV_BYTES;
    unsigned short* Xb = (unsigned short*)tail;
    unsigned short* Wb = (unsigned short*)(tail + XB_BYTES);
    char* small = full ? (tail + XB_BYTES + WB_BYTES) : tail;
    int* act  = (int*)small;
    int* nbr  = (int*)(small + NPTS * sizeof(int));
    int* cnt8 = (int*)(small + NPTS * sizeof(int) * (1 + KNN));
    int* cnt32 = cnt8 + EBLK;
    if (ws_size < need_base) return;

    count8_kernel<<<EBLK, 256, 0, stream>>>(mask, cnt8);
    count32_kernel<<<EBLK, 256, 0, stream>>>(mask, cnt8, cnt32);
    extract_kernel<<<EBLK, 256, 0, stream>>>(mask, cnt8, cnt32, act);
    if (full) {
        knn_cast_kernel<<<1024 + CASTBLKS, 256, 0, stream>>>(act, nbr, x, Wq, Wk, Wv, Xb, Wb);
        gemm_qkv64<<<dim3(64, 8, 3), 256, 0, stream>>>(Xb, Wb, qb, kb, vb);
    } else {
        knn_cast_kernel<<<1024, 256, 0, stream>>>(act, nbr, x, Wq, Wk, Wv,
                                                  (unsigned short*)nullptr, (unsigned short*)nullptr);
        gemm_qkv_f32<<<dim3(64, 8, 3), 256, 0, stream>>>(x, Wq, Wk, Wv, qb, kb, vb);
    }
    attn_kernel<<<dim3(BATCH * NPTS), 256, 0, stream>>>(qb, kb, vb, nbr, out,
                                                        out + (size_t)BATCH * NPTS * DMODEL);
}